// Round 2
// baseline (190.082 us; speedup 1.0000x reference)
//
#include <hip/hip_runtime.h>

#define N_RAYS 65536
#define N_PTS 128
#define FEAT 3
#define FAR_DELTA 1e10f

// 4 rays per wave: two 32-lane segments (rays base+seg) x two independent
// chains (rays base+2+seg). Each lane owns 4 consecutive samples -> float4
// loads (16B/lane coalescing sweet spot). Width-32 segmented exclusive scan
// (5 steps) + width-32 reduction (5 steps); two chains give 2x ILP on the
// dependent shuffle latency that bounded R1.
__global__ __launch_bounds__(256) void volrend_kernel(
    const float* __restrict__ depth,
    const float* __restrict__ density,
    const float* __restrict__ feature,
    float* __restrict__ out)
{
    const int wave = threadIdx.x >> 6;
    const int lane = threadIdx.x & 63;
    const int seg  = lane >> 5;        // 0 or 1: which ray of the pair
    const int s    = lane & 31;        // sub-lane within segment
    const int base = (blockIdx.x * 4 + wave) * 4;   // first of 4 rays

    const int rayA = base + seg;       // chain A ray
    const int rayB = base + 2 + seg;   // chain B ray

    // ---- loads (all independent, issued up front) ----
    const float4 dA = *(const float4*)(depth   + rayA * N_PTS + 4 * s);
    const float4 rA = *(const float4*)(density + rayA * N_PTS + 4 * s);
    const float4 dB = *(const float4*)(depth   + rayB * N_PTS + 4 * s);
    const float4 rB = *(const float4*)(density + rayB * N_PTS + 4 * s);
    const float4* fA = (const float4*)(feature + (size_t)rayA * (N_PTS * FEAT)) + 3 * s;
    const float4* fB = (const float4*)(feature + (size_t)rayB * (N_PTS * FEAT)) + 3 * s;
    const float4 fA0 = fA[0], fA1 = fA[1], fA2 = fA[2];
    const float4 fB0 = fB[0], fB1 = fB[1], fB2 = fB[2];

    // ---- deltas (needs next lane's d.x; segment-last lane uses sentinel) ----
    float nxA = __shfl_down(dA.x, 1);
    float nxB = __shfl_down(dB.x, 1);
    const bool last = (s == 31);
    float tA0 = rA.x * (dA.y - dA.x);
    float tA1 = rA.y * (dA.z - dA.y);
    float tA2 = rA.z * (dA.w - dA.z);
    float tA3 = rA.w * (last ? FAR_DELTA : (nxA - dA.w));
    float tB0 = rB.x * (dB.y - dB.x);
    float tB1 = rB.y * (dB.z - dB.y);
    float tB2 = rB.z * (dB.w - dB.z);
    float tB3 = rB.w * (last ? FAR_DELTA : (nxB - dB.w));

    // ---- exclusive segmented scan of per-lane tau sums (width 32) ----
    float pA = tA0 + tA1 + tA2 + tA3;
    float pB = tB0 + tB1 + tB2 + tB3;
    float eA = __shfl_up(pA, 1, 32);
    float eB = __shfl_up(pB, 1, 32);
    if (s == 0) { eA = 0.0f; eB = 0.0f; }
    #pragma unroll
    for (int off = 1; off < 32; off <<= 1) {
        float xA = __shfl_up(eA, off, 32);
        float xB = __shfl_up(eB, off, 32);
        if (s >= off) { eA += xA; eB += xB; }
    }
    // eA/eB = cumulative tau before this lane's first sample

    // ---- transmittance boundaries & weights (huge sentinel tau -> exp->0) ----
    float TA0 = __expf(-eA);
    float TA1 = __expf(-(eA + tA0));
    float TA2 = __expf(-(eA + tA0 + tA1));
    float TA3 = __expf(-(eA + tA0 + tA1 + tA2));
    float TA4 = __expf(-(eA + pA));
    float TB0 = __expf(-eB);
    float TB1 = __expf(-(eB + tB0));
    float TB2 = __expf(-(eB + tB0 + tB1));
    float TB3 = __expf(-(eB + tB0 + tB1 + tB2));
    float TB4 = __expf(-(eB + pB));
    float wA0 = TA0 - TA1, wA1 = TA1 - TA2, wA2 = TA2 - TA3, wA3 = TA3 - TA4;
    float wB0 = TB0 - TB1, wB1 = TB1 - TB2, wB2 = TB2 - TB3, wB3 = TB3 - TB4;

    // ---- weighted feature + depth accumulation ----
    // samples 4s..4s+3 rgb: (f0.x f0.y f0.z)(f0.w f1.x f1.y)(f1.z f1.w f2.x)(f2.y f2.z f2.w)
    float a0 = wA0 * fA0.x + wA1 * fA0.w + wA2 * fA1.z + wA3 * fA2.y;
    float a1 = wA0 * fA0.y + wA1 * fA1.x + wA2 * fA1.w + wA3 * fA2.z;
    float a2 = wA0 * fA0.z + wA1 * fA1.y + wA2 * fA2.x + wA3 * fA2.w;
    float a3 = wA0 * dA.x  + wA1 * dA.y  + wA2 * dA.z  + wA3 * dA.w;
    float b0 = wB0 * fB0.x + wB1 * fB0.w + wB2 * fB1.z + wB3 * fB2.y;
    float b1 = wB0 * fB0.y + wB1 * fB1.x + wB2 * fB1.w + wB3 * fB2.z;
    float b2 = wB0 * fB0.z + wB1 * fB1.y + wB2 * fB2.x + wB3 * fB2.w;
    float b3 = wB0 * dB.x  + wB1 * dB.y  + wB2 * dB.z  + wB3 * dB.w;

    // ---- width-32 reduction (lane s=0 of each segment ends up correct) ----
    #pragma unroll
    for (int off = 16; off > 0; off >>= 1) {
        a0 += __shfl_down(a0, off, 32);
        a1 += __shfl_down(a1, off, 32);
        a2 += __shfl_down(a2, off, 32);
        a3 += __shfl_down(a3, off, 32);
        b0 += __shfl_down(b0, off, 32);
        b1 += __shfl_down(b1, off, 32);
        b2 += __shfl_down(b2, off, 32);
        b3 += __shfl_down(b3, off, 32);
    }

    if (s == 0) {
        *(float4*)(out + (size_t)rayA * 4) = make_float4(a0, a1, a2, a3);
        *(float4*)(out + (size_t)rayB * 4) = make_float4(b0, b1, b2, b3);
    }
}

extern "C" void kernel_launch(void* const* d_in, const int* in_sizes, int n_in,
                              void* d_out, int out_size, void* d_ws, size_t ws_size,
                              hipStream_t stream) {
    const float* depth   = (const float*)d_in[0];
    const float* density = (const float*)d_in[1];
    const float* feature = (const float*)d_in[2];
    float* out = (float*)d_out;

    // 16 rays per 256-thread block (4 waves x 4 rays)
    dim3 grid(N_RAYS / 16);
    dim3 block(256);
    volrend_kernel<<<grid, block, 0, stream>>>(depth, density, feature, out);
}